// Round 12
// baseline (205.395 us; speedup 1.0000x reference)
//
#include <hip/hip_runtime.h>
#include <hip/hip_bf16.h>
#include <stdint.h>

typedef unsigned short u16;
typedef unsigned int u32;
typedef __attribute__((ext_vector_type(8))) __bf16 bf16x8;
typedef __attribute__((ext_vector_type(4))) float f32x4;
typedef __attribute__((ext_vector_type(16))) float f32x16;

#define B_ 4
#define T_ 2048
#define C_ 1024
#define H_ 16
#define D_ 64

__device__ __forceinline__ u16 f2bf(float f) {
  union { float f; u32 u; } v; v.f = f;
  u32 r = (v.u + 0x7fffu + ((v.u >> 16) & 1u)) >> 16;
  return (u16)r;
}

__device__ __forceinline__ float fexp2(float x) {
  float r;
  asm("v_exp_f32 %0, %1\n\ts_nop 0" : "=v"(r) : "v"(x));
  return r;
}

__device__ __forceinline__ u32 cvtpk(float lo, float hi2) {
  u32 r;
  asm("v_cvt_pk_bf16_f32 %0, %1, %2" : "=v"(r) : "v"(lo), "v"(hi2));
  return r;
}

__device__ __forceinline__ void gll16(const void* g, void* l) {
  __builtin_amdgcn_global_load_lds((const __attribute__((address_space(1))) void*)g,
                                   (__attribute__((address_space(3))) void*)l, 16, 0, 0);
}

// ---------------- fused prep: x fp32->bf16 convert + both weight transposes ----------
__global__ void k_prep(const float* __restrict__ x, u16* __restrict__ xb,
                       const float* __restrict__ wa, u16* __restrict__ waT,
                       const float* __restrict__ wp, u16* __restrict__ wpT) {
  __shared__ float tile[32][33];
  const int bid = blockIdx.x;
  const int tx = threadIdx.x, ty = threadIdx.y;
  if (bid < 2048) {
    const int tid = bid * 256 + ty * 32 + tx;
    const int n4 = (B_ * T_ * C_) / 4;
    for (int i = tid; i < n4; i += 2048 * 256) {
      float4 v = ((const float4*)x)[i];
      ushort4 o;
      o.x = f2bf(v.x); o.y = f2bf(v.y); o.z = f2bf(v.z); o.w = f2bf(v.w);
      ((ushort4*)xb)[i] = o;
    }
    return;
  }
  const float* src; u16* dst; int N, b2;
  if (bid < 5120) { b2 = bid - 2048; src = wa; dst = waT; N = 3 * C_; }
  else            { b2 = bid - 5120; src = wp; dst = wpT; N = C_; }
  const int K = C_;
  const int k0 = (b2 & 31) * 32, n0 = (b2 >> 5) * 32;
#pragma unroll
  for (int r = 0; r < 4; ++r) {
    int k = ty + r * 8;
    tile[k][tx] = src[(size_t)(k0 + k) * N + n0 + tx];
  }
  __syncthreads();
#pragma unroll
  for (int r = 0; r < 4; ++r) {
    int n = ty + r * 8;
    dst[(size_t)(n0 + n) * K + k0 + tx] = f2bf(tile[tx][n]);
  }
}

// ---------------- 128x128x32 bf16 MFMA GEMM, 2 waves x (64x128 per wave) -------------
// r12: LDS-throughput fix. Per-wave fragment tile 64x128 (4x8 frags) = 12 ds_read_b128
// per 32 MFMA vs old 8 per 16 -> 1.33x fewer LDS reads per FLOP (per-CU 96 -> 72 reads
// per K-interval). Same triple-buffer counted-vmcnt skeleton; stage = 8 gll16/thread
// -> in-loop vmcnt(8) (one stage in flight). 1D grid, bijective XCD-chunk swizzle.
template <int MODE>
__global__ __launch_bounds__(128) void k_gemm(
    const u16* __restrict__ A, const u16* __restrict__ BT, const float* __restrict__ bias,
    float* __restrict__ outF, u16* __restrict__ qb, u16* __restrict__ kb, u16* __restrict__ vbT,
    int M, int N, int K) {
  __shared__ u16 al[3][128 * 32];
  __shared__ u16 bl[3][128 * 32];
  const int tid = threadIdx.x;
  const int lane = tid & 63, wid = tid >> 6;   // 2 waves
  const int nbx = N >> 7;
  const int cpx = ((M >> 7) * nbx) >> 3;
  const int wg = blockIdx.x;
  const int lid = (wg & 7) * cpx + (wg >> 3);
  const int brow = (lid / nbx) * 128, bcol = (lid % nbx) * 128;
  const int wr = wid * 64;                      // wave owns rows wr..wr+63, all 128 cols
  const int lr = lane & 15, lg = lane >> 4, lk = lg * 8;
  f32x4 acc[4][8] = {};

  auto stage = [&](u16* ad, u16* bd, int t2) {
    const int kt = t2 * 32;
#pragma unroll
    for (int it = 0; it < 4; ++it) {
      int s = it * 128 + tid;                  // 512 slots per matrix, 4 per thread
      int row = s >> 2, col = (s & 3) * 8;
      gll16(A + (size_t)(brow + row) * K + kt + col, ad + (s & ~63) * 8);
      gll16(BT + (size_t)(bcol + row) * K + kt + col, bd + (s & ~63) * 8);
    }
  };

  const int nt = K / 32;
  stage(al[0], bl[0], 0);
  stage(al[1], bl[1], 1);

  for (int t = 0; t < nt; ++t) {
    if (t == nt - 1) { asm volatile("s_waitcnt vmcnt(0)" ::: "memory"); }
    else             { asm volatile("s_waitcnt vmcnt(8)" ::: "memory"); }
    __builtin_amdgcn_sched_barrier(0);
    __builtin_amdgcn_s_barrier();
    __builtin_amdgcn_sched_barrier(0);

    const int nxt = t + 2;
    if (nxt < nt) {
      const int ib = nxt % 3;
      stage(al[ib], bl[ib], nxt);
    }

    const u16* ab = al[t % 3];
    const u16* bb = bl[t % 3];
    bf16x8 af[4], bfr[8];
#pragma unroll
    for (int m = 0; m < 4; ++m) af[m] = *(const bf16x8*)&ab[(wr + m * 16 + lr) * 32 + lk];
#pragma unroll
    for (int n = 0; n < 8; ++n) bfr[n] = *(const bf16x8*)&bb[(n * 16 + lr) * 32 + lk];

    __builtin_amdgcn_s_setprio(1);
#pragma unroll
    for (int m = 0; m < 4; ++m)
#pragma unroll
      for (int n = 0; n < 8; ++n)
        acc[m][n] = __builtin_amdgcn_mfma_f32_16x16x32_bf16(af[m], bfr[n], acc[m][n], 0, 0, 0);
    __builtin_amdgcn_s_setprio(0);
  }

#pragma unroll
  for (int m = 0; m < 4; ++m) {
    int row = brow + wr + m * 16 + lg * 4;
#pragma unroll
    for (int n = 0; n < 8; ++n) {
      int col = bcol + n * 16 + lr;
      float bs = bias[col];
      if (MODE == 0) {
#pragma unroll
        for (int r = 0; r < 4; ++r)
          outF[(size_t)(row + r) * N + col] = acc[m][n][r] + bs;
      } else {
        int sec = col >> 10, cc = col & 1023;
        int h = cc >> 6, dd = cc & 63;
        int b = row >> 11, t = row & 2047;
        size_t bh = (size_t)(b * H_ + h);
        if (sec < 2) {
          u16* dst = (sec == 0 ? qb : kb) + (bh * T_ + t) * D_ + dd;
#pragma unroll
          for (int r = 0; r < 4; ++r) dst[(size_t)r * D_] = f2bf(acc[m][n][r] + bs);
        } else {
          ushort4 pk;
          pk.x = f2bf(acc[m][n][0] + bs);
          pk.y = f2bf(acc[m][n][1] + bs);
          pk.z = f2bf(acc[m][n][2] + bs);
          pk.w = f2bf(acc[m][n][3] + bs);
          *(ushort4*)&vbT[(bh * D_ + dd) * T_ + t] = pk;
        }
      }
    }
  }
}

// ---------------- flash attention (causal), swapped-QK 32x32, balanced pairing ----
// r10 form (measured best): double-buffer + per-tile __syncthreads.
__global__ __launch_bounds__(256) void k_attn(
    const u16* __restrict__ qb, const u16* __restrict__ kb,
    const u16* __restrict__ vbT, u16* __restrict__ attb) {
  __shared__ u16 kl0[64 * 64], kl1[64 * 64];
  __shared__ u16 vl0[64 * 64], vl1[64 * 64];
  const int lane = threadIdx.x & 63, wid = threadIdx.x >> 6;
  const int w = blockIdx.x;                  // 512 blocks = 8 XCD chunks x 64
  const int lid = (w & 7) * 64 + (w >> 3);
  const int bh = lid >> 3, qpair = lid & 7;
  const int b = bh >> 4, h = bh & 15;
  const int l31 = lane & 31, hi = lane >> 5;
  const int sw3 = l31 & 7;

  const float SC = 0.18033688f;  // 0.125 * log2(e)

  const u16* kbase = kb + (size_t)bh * T_ * D_;
  const u16* vbase = vbT + (size_t)bh * D_ * T_;

  auto stage = [&](u16* kd, u16* vd, int kt) {
    const int k0 = kt * 64;
#pragma unroll
    for (int it = 0; it < 2; ++it) {
      int cbase = (wid * 2 + it) * 64;
      int c = cbase + lane;
      int cs = (c & ~7) | ((c ^ (c >> 3)) & 7);  // source chunk = j ^ (row&7)
      gll16(kbase + (size_t)k0 * D_ + (size_t)cs * 8, kd + cbase * 8);
      int vrow = cs >> 3, vcol = (cs & 7) * 8;
      gll16(vbase + (size_t)vrow * T_ + k0 + vcol, vd + cbase * 8);
    }
  };

  auto pack = [&](const f32x16& s, bf16x8* out) {
#pragma unroll
    for (int cc = 0; cc < 2; ++cc) {
      const int rb = cc * 8;
      u32 a  = cvtpk(s[rb + 0], s[rb + 1]);
      u32 c  = cvtpk(s[rb + 2], s[rb + 3]);
      u32 bb = cvtpk(s[rb + 4], s[rb + 5]);
      u32 d  = cvtpk(s[rb + 6], s[rb + 7]);
      u32 as = __shfl_xor(a, 32, 64), cs = __shfl_xor(c, 32, 64);
      u32 bs = __shfl_xor(bb, 32, 64), ds = __shfl_xor(d, 32, 64);
      union { u32 u[4]; bf16x8 v; } t;
      t.u[0] = hi ? bs : a;
      t.u[1] = hi ? ds : c;
      t.u[2] = hi ? bb : as;
      t.u[3] = hi ? d : cs;
      out[cc] = t.v;
    }
  };

#pragma unroll 1
  for (int pass = 0; pass < 2; ++pass) {
    const int qbk = pass ? (15 - qpair) : qpair;
    const int qw = qbk * 128 + wid * 32;

    const u16* qrow = qb + ((size_t)bh * T_ + qw + l31) * D_ + hi * 8;
    bf16x8 qf[4];
#pragma unroll
    for (int j = 0; j < 4; ++j) qf[j] = *(const bf16x8*)(qrow + j * 16);

    float lsum = 0.f;
    f32x16 o0 = {}, o1 = {};

    const int nt = 2 * qbk + 2;
    const int lastkt = (qw + 31) >> 6;

    auto compute = [&](const u16* kl, const u16* vl, int kt) {
      const int k0 = kt * 64;
      f32x16 s0 = {}, s1 = {};
      __builtin_amdgcn_s_setprio(1);
#pragma unroll
      for (int j = 0; j < 4; ++j) {
        const int ch = ((2 * j + hi) ^ sw3) << 3;
        const bf16x8 kf0 = *(const bf16x8*)&kl[l31 * 64 + ch];
        const bf16x8 kf1 = *(const bf16x8*)&kl[(l31 + 32) * 64 + ch];
        s0 = __builtin_amdgcn_mfma_f32_32x32x16_bf16(kf0, qf[j], s0, 0, 0, 0);
        s1 = __builtin_amdgcn_mfma_f32_32x32x16_bf16(kf1, qf[j], s1, 0, 0, 0);
      }
      __builtin_amdgcn_s_setprio(0);

      if (kt == lastkt) {  // causal mask, diagonal tile only
        const int q = qw + l31;
#pragma unroll
        for (int r = 0; r < 16; ++r) {
          const int kv = k0 + (r & 3) + 8 * (r >> 2) + 4 * hi;
          if (kv > q) s0[r] = -3e38f;      // *SC -> -5.4e37, exp2 -> 0
          if (kv + 32 > q) s1[r] = -3e38f;
        }
      }

      // --- s0: exp, sum-tree, pack, PV (kv 0..31) ---
#pragma unroll
      for (int r = 0; r < 16; ++r) s0[r] = fexp2(s0[r] * SC);
      float t0[8];
#pragma unroll
      for (int r = 0; r < 8; ++r) t0[r] = s0[r] + s0[r + 8];
#pragma unroll
      for (int w2 = 4; w2 >= 1; w2 >>= 1)
#pragma unroll
        for (int r = 0; r < 4; ++r)
          if (r < w2) t0[r] += t0[r + w2];

      bf16x8 pb0[2];
      pack(s0, pb0);
      __builtin_amdgcn_s_setprio(1);
#pragma unroll
      for (int c = 0; c < 2; ++c) {
        const int ch = ((2 * c + hi) ^ sw3) << 3;
        const bf16x8 vf0 = *(const bf16x8*)&vl[l31 * 64 + ch];
        const bf16x8 vf1 = *(const bf16x8*)&vl[(l31 + 32) * 64 + ch];
        o0 = __builtin_amdgcn_mfma_f32_32x32x16_bf16(vf0, pb0[c], o0, 0, 0, 0);
        o1 = __builtin_amdgcn_mfma_f32_32x32x16_bf16(vf1, pb0[c], o1, 0, 0, 0);
      }
      __builtin_amdgcn_s_setprio(0);

      // --- s1: exp/sum/pack on VALU while PV(s0) drains the MFMA pipe ---
#pragma unroll
      for (int r = 0; r < 16; ++r) s1[r] = fexp2(s1[r] * SC);
      float t1[8];
#pragma unroll
      for (int r = 0; r < 8; ++r) t1[r] = s1[r] + s1[r + 8];
#pragma unroll
      for (int w2 = 4; w2 >= 1; w2 >>= 1)
#pragma unroll
        for (int r = 0; r < 4; ++r)
          if (r < w2) t1[r] += t1[r + w2];

      bf16x8 pb1[2];
      pack(s1, pb1);
      __builtin_amdgcn_s_setprio(1);
#pragma unroll
      for (int c = 2; c < 4; ++c) {
        const int ch = ((2 * c + hi) ^ sw3) << 3;
        const bf16x8 vf0 = *(const bf16x8*)&vl[l31 * 64 + ch];
        const bf16x8 vf1 = *(const bf16x8*)&vl[(l31 + 32) * 64 + ch];
        o0 = __builtin_amdgcn_mfma_f32_32x32x16_bf16(vf0, pb1[c - 2], o0, 0, 0, 0);
        o1 = __builtin_amdgcn_mfma_f32_32x32x16_bf16(vf1, pb1[c - 2], o1, 0, 0, 0);
      }
      __builtin_amdgcn_s_setprio(0);

      float ps = t0[0] + t1[0];
      ps += __shfl_xor(ps, 32, 64);
      lsum += ps;
    };

    stage(kl0, vl0, 0);
    __syncthreads();
    int kt = 0;
    while (true) {
      if (kt + 1 < nt) stage(kl1, vl1, kt + 1);
      if (kt <= lastkt) compute(kl0, vl0, kt);
      __syncthreads();
      if (++kt >= nt) break;
      if (kt + 1 < nt) stage(kl0, vl0, kt + 1);
      if (kt <= lastkt) compute(kl1, vl1, kt);
      __syncthreads();
      if (++kt >= nt) break;
    }

    const float inv = 1.0f / lsum;
    u16* orow = attb + ((size_t)b * T_ + qw + l31) * C_ + h * D_;
#pragma unroll
    for (int rg = 0; rg < 4; ++rg) {
      ushort4 w0, w1;
      w0.x = f2bf(o0[rg * 4 + 0] * inv); w0.y = f2bf(o0[rg * 4 + 1] * inv);
      w0.z = f2bf(o0[rg * 4 + 2] * inv); w0.w = f2bf(o0[rg * 4 + 3] * inv);
      w1.x = f2bf(o1[rg * 4 + 0] * inv); w1.y = f2bf(o1[rg * 4 + 1] * inv);
      w1.z = f2bf(o1[rg * 4 + 2] * inv); w1.w = f2bf(o1[rg * 4 + 3] * inv);
      const int d0 = rg * 8 + hi * 4;
      *(ushort4*)(orow + d0) = w0;
      *(ushort4*)(orow + d0 + 32) = w1;
    }
  }
}

extern "C" void kernel_launch(void* const* d_in, const int* in_sizes, int n_in,
                              void* d_out, int out_size, void* d_ws, size_t ws_size,
                              hipStream_t stream) {
  const float* x = (const float*)d_in[0];
  const float* w_attn = (const float*)d_in[1];
  const float* b_attn = (const float*)d_in[2];
  const float* w_proj = (const float*)d_in[3];
  const float* b_proj = (const float*)d_in[4];
  float* out = (float*)d_out;

  char* ws = (char*)d_ws;
  const size_t MB = 1024 * 1024;
  u16* xb   = (u16*)(ws);             // 16 MB; reused as attb after GEMM1
  u16* attb = xb;
  u16* waT  = (u16*)(ws + 16 * MB);   // 6 MB
  u16* wpT  = (u16*)(ws + 22 * MB);   // 2 MB
  u16* qb   = (u16*)(ws + 24 * MB);   // 16 MB [B,H,T,D]
  u16* kb   = (u16*)(ws + 40 * MB);   // 16 MB [B,H,T,D]
  u16* vbT  = (u16*)(ws + 56 * MB);   // 16 MB [B,H,D,T]

  k_prep<<<6144, dim3(32, 8), 0, stream>>>(x, xb, w_attn, waT, w_proj, wpT);

  // GEMM1: 64 x 24 = 1536 blocks x 128 threads (2 waves), XCD-chunk swizzled
  k_gemm<1><<<(8192 / 128) * (3 * C_ / 128), 128, 0, stream>>>(
      xb, waT, b_attn, nullptr, qb, kb, vbT, B_ * T_, 3 * C_, C_);

  k_attn<<<512, 256, 0, stream>>>(qb, kb, vbT, attb);

  // GEMM2: 64 x 8 = 512 blocks x 128 threads, XCD-chunk swizzled
  k_gemm<0><<<(8192 / 128) * (C_ / 128), 128, 0, stream>>>(
      attb, wpT, b_proj, out, nullptr, nullptr, nullptr, B_ * T_, C_, C_);
}

// Round 13
// 167.248 us; speedup vs baseline: 1.2281x; 1.2281x over previous
//
#include <hip/hip_runtime.h>
#include <hip/hip_bf16.h>
#include <stdint.h>

typedef unsigned short u16;
typedef unsigned int u32;
typedef __attribute__((ext_vector_type(8))) __bf16 bf16x8;
typedef __attribute__((ext_vector_type(4))) float f32x4;
typedef __attribute__((ext_vector_type(16))) float f32x16;

#define B_ 4
#define T_ 2048
#define C_ 1024
#define H_ 16
#define D_ 64

__device__ __forceinline__ u16 f2bf(float f) {
  union { float f; u32 u; } v; v.f = f;
  u32 r = (v.u + 0x7fffu + ((v.u >> 16) & 1u)) >> 16;
  return (u16)r;
}

__device__ __forceinline__ float fexp2(float x) {
  float r;
  asm("v_exp_f32 %0, %1\n\ts_nop 0" : "=v"(r) : "v"(x));
  return r;
}

__device__ __forceinline__ u32 cvtpk(float lo, float hi2) {
  u32 r;
  asm("v_cvt_pk_bf16_f32 %0, %1, %2" : "=v"(r) : "v"(lo), "v"(hi2));
  return r;
}

__device__ __forceinline__ void gll16(const void* g, void* l) {
  __builtin_amdgcn_global_load_lds((const __attribute__((address_space(1))) void*)g,
                                   (__attribute__((address_space(3))) void*)l, 16, 0, 0);
}

// ---------------- fused prep: x fp32->bf16 convert + both weight transposes ----------
__global__ void k_prep(const float* __restrict__ x, u16* __restrict__ xb,
                       const float* __restrict__ wa, u16* __restrict__ waT,
                       const float* __restrict__ wp, u16* __restrict__ wpT) {
  __shared__ float tile[32][33];
  const int bid = blockIdx.x;
  const int tx = threadIdx.x, ty = threadIdx.y;
  if (bid < 2048) {
    const int tid = bid * 256 + ty * 32 + tx;
    const int n4 = (B_ * T_ * C_) / 4;
    for (int i = tid; i < n4; i += 2048 * 256) {
      float4 v = ((const float4*)x)[i];
      ushort4 o;
      o.x = f2bf(v.x); o.y = f2bf(v.y); o.z = f2bf(v.z); o.w = f2bf(v.w);
      ((ushort4*)xb)[i] = o;
    }
    return;
  }
  const float* src; u16* dst; int N, b2;
  if (bid < 5120) { b2 = bid - 2048; src = wa; dst = waT; N = 3 * C_; }
  else            { b2 = bid - 5120; src = wp; dst = wpT; N = C_; }
  const int K = C_;
  const int k0 = (b2 & 31) * 32, n0 = (b2 >> 5) * 32;
#pragma unroll
  for (int r = 0; r < 4; ++r) {
    int k = ty + r * 8;
    tile[k][tx] = src[(size_t)(k0 + k) * N + n0 + tx];
  }
  __syncthreads();
#pragma unroll
  for (int r = 0; r < 4; ++r) {
    int n = ty + r * 8;
    dst[(size_t)(n0 + n) * K + k0 + tx] = f2bf(tile[tx][n]);
  }
}

// ---------------- 128x128x32 bf16 MFMA GEMM, triple-buffered counted-vmcnt pipeline --
// r13: + LDS slot-XOR swizzle. The [128][32] bf16 tile (64B rows) put a 16-lane frag
// group on 2 of 8 16B-slot positions (slot&7 = (row&1)*4 + chunk) -> ~8-way conflict
// (measured +4 cyc/read, 6.3M conflict-cycles). Fix: store logical chunk j of row r at
// physical slot r*4 + (j ^ ((r>>1)&3)) via inverse-swizzled GLOBAL source (linear gll16
// dest, rule 21); read offset (lg ^ ((lr>>1)&3))*16B -> 16 lanes cover all 8 slot
// positions -> 2 lanes/bank = free. Schedule/geometry/epilogue unchanged from r10.
template <int MODE>
__global__ __launch_bounds__(256) void k_gemm(
    const u16* __restrict__ A, const u16* __restrict__ BT, const float* __restrict__ bias,
    float* __restrict__ outF, u16* __restrict__ qb, u16* __restrict__ kb, u16* __restrict__ vbT,
    int M, int N, int K) {
  __shared__ u16 al[3][128 * 32];
  __shared__ u16 bl[3][128 * 32];
  const int lane = threadIdx.x & 63, wid = threadIdx.x >> 6;
  const int nbx = N >> 7;
  const int cpx = ((M >> 7) * nbx) >> 3;
  const int wg = blockIdx.x;
  const int lid = (wg & 7) * cpx + (wg >> 3);
  const int brow = (lid / nbx) * 128, bcol = (lid % nbx) * 128;
  const int wr = (wid >> 1) * 64, wc = (wid & 1) * 64;
  const int lr = lane & 15, lg = lane >> 4;
  const int ck = (lg ^ ((lr >> 1) & 3)) * 8;   // swizzled chunk offset (elements)
  f32x4 acc[4][4] = {};

  auto stage = [&](u16* ad, u16* bd, int t2) {
    const int kt = t2 * 32;
#pragma unroll
    for (int it = 0; it < 2; ++it) {
      int cbase = (wid * 2 + it) * 64;
      int c = cbase + lane;
      int row = c >> 2;
      int j = (c & 3) ^ ((row >> 1) & 3);      // logical chunk for this physical slot
      int col = j * 8;
      gll16(A + (size_t)(brow + row) * K + kt + col, ad + cbase * 8);
      gll16(BT + (size_t)(bcol + row) * K + kt + col, bd + cbase * 8);
    }
  };

  const int nt = K / 32;
  stage(al[0], bl[0], 0);
  stage(al[1], bl[1], 1);

  for (int t = 0; t < nt; ++t) {
    if (t == nt - 1) { asm volatile("s_waitcnt vmcnt(0)" ::: "memory"); }
    else             { asm volatile("s_waitcnt vmcnt(4)" ::: "memory"); }
    __builtin_amdgcn_sched_barrier(0);
    __builtin_amdgcn_s_barrier();
    __builtin_amdgcn_sched_barrier(0);

    const int nxt = t + 2;
    if (nxt < nt) {
      const int ib = nxt % 3;
      stage(al[ib], bl[ib], nxt);
    }

    const u16* ab = al[t % 3];
    const u16* bb = bl[t % 3];
    bf16x8 af[4], bfr[4];
#pragma unroll
    for (int m = 0; m < 4; ++m) af[m] = *(const bf16x8*)&ab[(wr + m * 16 + lr) * 32 + ck];
#pragma unroll
    for (int n = 0; n < 4; ++n) bfr[n] = *(const bf16x8*)&bb[(wc + n * 16 + lr) * 32 + ck];

    __builtin_amdgcn_s_setprio(1);
#pragma unroll
    for (int m = 0; m < 4; ++m)
#pragma unroll
      for (int n = 0; n < 4; ++n)
        acc[m][n] = __builtin_amdgcn_mfma_f32_16x16x32_bf16(af[m], bfr[n], acc[m][n], 0, 0, 0);
    __builtin_amdgcn_s_setprio(0);
  }

#pragma unroll
  for (int m = 0; m < 4; ++m) {
    int row = brow + wr + m * 16 + lg * 4;
#pragma unroll
    for (int n = 0; n < 4; ++n) {
      int col = bcol + wc + n * 16 + lr;
      float bs = bias[col];
      if (MODE == 0) {
#pragma unroll
        for (int r = 0; r < 4; ++r)
          outF[(size_t)(row + r) * N + col] = acc[m][n][r] + bs;
      } else {
        int sec = col >> 10, cc = col & 1023;
        int h = cc >> 6, dd = cc & 63;
        int b = row >> 11, t = row & 2047;
        size_t bh = (size_t)(b * H_ + h);
        if (sec < 2) {
          u16* dst = (sec == 0 ? qb : kb) + (bh * T_ + t) * D_ + dd;
#pragma unroll
          for (int r = 0; r < 4; ++r) dst[(size_t)r * D_] = f2bf(acc[m][n][r] + bs);
        } else {
          ushort4 pk;
          pk.x = f2bf(acc[m][n][0] + bs);
          pk.y = f2bf(acc[m][n][1] + bs);
          pk.z = f2bf(acc[m][n][2] + bs);
          pk.w = f2bf(acc[m][n][3] + bs);
          *(ushort4*)&vbT[(bh * D_ + dd) * T_ + t] = pk;
        }
      }
    }
  }
}

// ---------------- flash attention (causal), swapped-QK 32x32, balanced pairing ----
// r10 form (measured best): double-buffer + per-tile __syncthreads.
__global__ __launch_bounds__(256) void k_attn(
    const u16* __restrict__ qb, const u16* __restrict__ kb,
    const u16* __restrict__ vbT, u16* __restrict__ attb) {
  __shared__ u16 kl0[64 * 64], kl1[64 * 64];
  __shared__ u16 vl0[64 * 64], vl1[64 * 64];
  const int lane = threadIdx.x & 63, wid = threadIdx.x >> 6;
  const int w = blockIdx.x;                  // 512 blocks = 8 XCD chunks x 64
  const int lid = (w & 7) * 64 + (w >> 3);
  const int bh = lid >> 3, qpair = lid & 7;
  const int b = bh >> 4, h = bh & 15;
  const int l31 = lane & 31, hi = lane >> 5;
  const int sw3 = l31 & 7;

  const float SC = 0.18033688f;  // 0.125 * log2(e)

  const u16* kbase = kb + (size_t)bh * T_ * D_;
  const u16* vbase = vbT + (size_t)bh * D_ * T_;

  auto stage = [&](u16* kd, u16* vd, int kt) {
    const int k0 = kt * 64;
#pragma unroll
    for (int it = 0; it < 2; ++it) {
      int cbase = (wid * 2 + it) * 64;
      int c = cbase + lane;
      int cs = (c & ~7) | ((c ^ (c >> 3)) & 7);  // source chunk = j ^ (row&7)
      gll16(kbase + (size_t)k0 * D_ + (size_t)cs * 8, kd + cbase * 8);
      int vrow = cs >> 3, vcol = (cs & 7) * 8;
      gll16(vbase + (size_t)vrow * T_ + k0 + vcol, vd + cbase * 8);
    }
  };

  auto pack = [&](const f32x16& s, bf16x8* out) {
#pragma unroll
    for (int cc = 0; cc < 2; ++cc) {
      const int rb = cc * 8;
      u32 a  = cvtpk(s[rb + 0], s[rb + 1]);
      u32 c  = cvtpk(s[rb + 2], s[rb + 3]);
      u32 bb = cvtpk(s[rb + 4], s[rb + 5]);
      u32 d  = cvtpk(s[rb + 6], s[rb + 7]);
      u32 as = __shfl_xor(a, 32, 64), cs = __shfl_xor(c, 32, 64);
      u32 bs = __shfl_xor(bb, 32, 64), ds = __shfl_xor(d, 32, 64);
      union { u32 u[4]; bf16x8 v; } t;
      t.u[0] = hi ? bs : a;
      t.u[1] = hi ? ds : c;
      t.u[2] = hi ? bb : as;
      t.u[3] = hi ? d : cs;
      out[cc] = t.v;
    }
  };

#pragma unroll 1
  for (int pass = 0; pass < 2; ++pass) {
    const int qbk = pass ? (15 - qpair) : qpair;
    const int qw = qbk * 128 + wid * 32;

    const u16* qrow = qb + ((size_t)bh * T_ + qw + l31) * D_ + hi * 8;
    bf16x8 qf[4];
#pragma unroll
    for (int j = 0; j < 4; ++j) qf[j] = *(const bf16x8*)(qrow + j * 16);

    float lsum = 0.f;
    f32x16 o0 = {}, o1 = {};

    const int nt = 2 * qbk + 2;
    const int lastkt = (qw + 31) >> 6;

    auto compute = [&](const u16* kl, const u16* vl, int kt) {
      const int k0 = kt * 64;
      f32x16 s0 = {}, s1 = {};
      __builtin_amdgcn_s_setprio(1);
#pragma unroll
      for (int j = 0; j < 4; ++j) {
        const int ch = ((2 * j + hi) ^ sw3) << 3;
        const bf16x8 kf0 = *(const bf16x8*)&kl[l31 * 64 + ch];
        const bf16x8 kf1 = *(const bf16x8*)&kl[(l31 + 32) * 64 + ch];
        s0 = __builtin_amdgcn_mfma_f32_32x32x16_bf16(kf0, qf[j], s0, 0, 0, 0);
        s1 = __builtin_amdgcn_mfma_f32_32x32x16_bf16(kf1, qf[j], s1, 0, 0, 0);
      }
      __builtin_amdgcn_s_setprio(0);

      if (kt == lastkt) {  // causal mask, diagonal tile only
        const int q = qw + l31;
#pragma unroll
        for (int r = 0; r < 16; ++r) {
          const int kv = k0 + (r & 3) + 8 * (r >> 2) + 4 * hi;
          if (kv > q) s0[r] = -3e38f;      // *SC -> -5.4e37, exp2 -> 0
          if (kv + 32 > q) s1[r] = -3e38f;
        }
      }

      // --- s0: exp, sum-tree, pack, PV (kv 0..31) ---
#pragma unroll
      for (int r = 0; r < 16; ++r) s0[r] = fexp2(s0[r] * SC);
      float t0[8];
#pragma unroll
      for (int r = 0; r < 8; ++r) t0[r] = s0[r] + s0[r + 8];
#pragma unroll
      for (int w2 = 4; w2 >= 1; w2 >>= 1)
#pragma unroll
        for (int r = 0; r < 4; ++r)
          if (r < w2) t0[r] += t0[r + w2];

      bf16x8 pb0[2];
      pack(s0, pb0);
      __builtin_amdgcn_s_setprio(1);
#pragma unroll
      for (int c = 0; c < 2; ++c) {
        const int ch = ((2 * c + hi) ^ sw3) << 3;
        const bf16x8 vf0 = *(const bf16x8*)&vl[l31 * 64 + ch];
        const bf16x8 vf1 = *(const bf16x8*)&vl[(l31 + 32) * 64 + ch];
        o0 = __builtin_amdgcn_mfma_f32_32x32x16_bf16(vf0, pb0[c], o0, 0, 0, 0);
        o1 = __builtin_amdgcn_mfma_f32_32x32x16_bf16(vf1, pb0[c], o1, 0, 0, 0);
      }
      __builtin_amdgcn_s_setprio(0);

      // --- s1: exp/sum/pack on VALU while PV(s0) drains the MFMA pipe ---
#pragma unroll
      for (int r = 0; r < 16; ++r) s1[r] = fexp2(s1[r] * SC);
      float t1[8];
#pragma unroll
      for (int r = 0; r < 8; ++r) t1[r] = s1[r] + s1[r + 8];
#pragma unroll
      for (int w2 = 4; w2 >= 1; w2 >>= 1)
#pragma unroll
        for (int r = 0; r < 4; ++r)
          if (r < w2) t1[r] += t1[r + w2];

      bf16x8 pb1[2];
      pack(s1, pb1);
      __builtin_amdgcn_s_setprio(1);
#pragma unroll
      for (int c = 2; c < 4; ++c) {
        const int ch = ((2 * c + hi) ^ sw3) << 3;
        const bf16x8 vf0 = *(const bf16x8*)&vl[l31 * 64 + ch];
        const bf16x8 vf1 = *(const bf16x8*)&vl[(l31 + 32) * 64 + ch];
        o0 = __builtin_amdgcn_mfma_f32_32x32x16_bf16(vf0, pb1[c - 2], o0, 0, 0, 0);
        o1 = __builtin_amdgcn_mfma_f32_32x32x16_bf16(vf1, pb1[c - 2], o1, 0, 0, 0);
      }
      __builtin_amdgcn_s_setprio(0);

      float ps = t0[0] + t1[0];
      ps += __shfl_xor(ps, 32, 64);
      lsum += ps;
    };

    stage(kl0, vl0, 0);
    __syncthreads();
    int kt = 0;
    while (true) {
      if (kt + 1 < nt) stage(kl1, vl1, kt + 1);
      if (kt <= lastkt) compute(kl0, vl0, kt);
      __syncthreads();
      if (++kt >= nt) break;
      if (kt + 1 < nt) stage(kl0, vl0, kt + 1);
      if (kt <= lastkt) compute(kl1, vl1, kt);
      __syncthreads();
      if (++kt >= nt) break;
    }

    const float inv = 1.0f / lsum;
    u16* orow = attb + ((size_t)b * T_ + qw + l31) * C_ + h * D_;
#pragma unroll
    for (int rg = 0; rg < 4; ++rg) {
      ushort4 w0, w1;
      w0.x = f2bf(o0[rg * 4 + 0] * inv); w0.y = f2bf(o0[rg * 4 + 1] * inv);
      w0.z = f2bf(o0[rg * 4 + 2] * inv); w0.w = f2bf(o0[rg * 4 + 3] * inv);
      w1.x = f2bf(o1[rg * 4 + 0] * inv); w1.y = f2bf(o1[rg * 4 + 1] * inv);
      w1.z = f2bf(o1[rg * 4 + 2] * inv); w1.w = f2bf(o1[rg * 4 + 3] * inv);
      const int d0 = rg * 8 + hi * 4;
      *(ushort4*)(orow + d0) = w0;
      *(ushort4*)(orow + d0 + 32) = w1;
    }
  }
}

extern "C" void kernel_launch(void* const* d_in, const int* in_sizes, int n_in,
                              void* d_out, int out_size, void* d_ws, size_t ws_size,
                              hipStream_t stream) {
  const float* x = (const float*)d_in[0];
  const float* w_attn = (const float*)d_in[1];
  const float* b_attn = (const float*)d_in[2];
  const float* w_proj = (const float*)d_in[3];
  const float* b_proj = (const float*)d_in[4];
  float* out = (float*)d_out;

  char* ws = (char*)d_ws;
  const size_t MB = 1024 * 1024;
  u16* xb   = (u16*)(ws);             // 16 MB; reused as attb after GEMM1
  u16* attb = xb;
  u16* waT  = (u16*)(ws + 16 * MB);   // 6 MB
  u16* wpT  = (u16*)(ws + 22 * MB);   // 2 MB
  u16* qb   = (u16*)(ws + 24 * MB);   // 16 MB [B,H,T,D]
  u16* kb   = (u16*)(ws + 40 * MB);   // 16 MB [B,H,T,D]
  u16* vbT  = (u16*)(ws + 56 * MB);   // 16 MB [B,H,D,T]

  k_prep<<<6144, dim3(32, 8), 0, stream>>>(x, xb, w_attn, waT, w_proj, wpT);

  // GEMM1: 64 x 24 = 1536 blocks (1D, XCD-chunk swizzled)
  k_gemm<1><<<(8192 / 128) * (3 * C_ / 128), 256, 0, stream>>>(
      xb, waT, b_attn, nullptr, qb, kb, vbT, B_ * T_, 3 * C_, C_);

  k_attn<<<512, 256, 0, stream>>>(qb, kb, vbT, attb);

  // GEMM2: 64 x 8 = 512 blocks (1D, XCD-chunk swizzled)
  k_gemm<0><<<(8192 / 128) * (C_ / 128), 256, 0, stream>>>(
      attb, wpT, b_proj, out, nullptr, nullptr, nullptr, B_ * T_, C_, C_);
}